// Round 1
// baseline (49.661 us; speedup 1.0000x reference)
//
#include <hip/hip_runtime.h>

// Comb filter: y[n] = x[n-D] + f*y[n-D], y[n]=0 for n<D.
// N = 16777216, D = 4096 -> 4096 independent chains of K = 4096 steps each.
// Chain c, step k: a_k = x[k*D + c]; y_0 = 0; y_{k+1} = f*y_k + a_k;
// output[k*D + c] = y_k.
//
// Parallel linear-recurrence scan:
//   Phase 1: per (segment s, chain c) carry  C = sum_j f^{L-1-j} a_{sL+j}
//   Phase 2: per chain, serial scan over S segments: Y_{s+1} = f^L * Y_s + C_s
//   Phase 3: per (segment, chain) replay exact recurrence from Y_s, write y.

#define N_TOTAL 16777216
#define D       4096
#define K_STEPS (N_TOTAL / D)   // 4096
#define SEGS    128             // segments per chain
#define SEGLEN  (K_STEPS / SEGS) // 32 steps per segment
#define D4      (D / 4)         // 1024 float4 per k-row

// 2 MiB + 2 MiB scratch in device globals (fully rewritten every call).
__device__ float g_carry[SEGS * D];
__device__ float g_ystart[SEGS * D];

__global__ __launch_bounds__(256)
void comb_carry(const float* __restrict__ x, const float* __restrict__ fptr) {
    const float f = fptr[0];
    const int c4 = blockIdx.x * 256 + threadIdx.x;   // float4 chain-group index
    const int s  = blockIdx.y;
    const float4* __restrict__ xp = (const float4*)x;
    int base = s * SEGLEN * D4 + c4;

    float4 acc = make_float4(0.f, 0.f, 0.f, 0.f);
    #pragma unroll 8
    for (int k = 0; k < SEGLEN; ++k) {
        float4 a = xp[base + k * D4];
        acc.x = f * acc.x + a.x;
        acc.y = f * acc.y + a.y;
        acc.z = f * acc.z + a.z;
        acc.w = f * acc.w + a.w;
    }
    ((float4*)g_carry)[s * D4 + c4] = acc;
}

__global__ __launch_bounds__(256)
void comb_scan(const float* __restrict__ fptr) {
    const float f = fptr[0];
    float fL = 1.f;
    #pragma unroll
    for (int i = 0; i < SEGLEN; ++i) fL *= f;

    const int c4 = blockIdx.x * 256 + threadIdx.x;   // 0 .. D4-1
    float4 Y = make_float4(0.f, 0.f, 0.f, 0.f);
    for (int s = 0; s < SEGS; ++s) {
        ((float4*)g_ystart)[s * D4 + c4] = Y;
        float4 C = ((const float4*)g_carry)[s * D4 + c4];
        Y.x = fL * Y.x + C.x;
        Y.y = fL * Y.y + C.y;
        Y.z = fL * Y.z + C.z;
        Y.w = fL * Y.w + C.w;
    }
}

__global__ __launch_bounds__(256)
void comb_emit(const float* __restrict__ x, const float* __restrict__ fptr,
               float* __restrict__ out) {
    const float f = fptr[0];
    const int c4 = blockIdx.x * 256 + threadIdx.x;
    const int s  = blockIdx.y;
    const float4* __restrict__ xp = (const float4*)x;
    float4* __restrict__ op = (float4*)out;
    int base = s * SEGLEN * D4 + c4;

    float4 y = ((const float4*)g_ystart)[s * D4 + c4];
    #pragma unroll 8
    for (int k = 0; k < SEGLEN; ++k) {
        int idx = base + k * D4;
        op[idx] = y;
        float4 a = xp[idx];
        y.x = f * y.x + a.x;
        y.y = f * y.y + a.y;
        y.z = f * y.z + a.z;
        y.w = f * y.w + a.w;
    }
}

extern "C" void kernel_launch(void* const* d_in, const int* in_sizes, int n_in,
                              void* d_out, int out_size, void* d_ws, size_t ws_size,
                              hipStream_t stream) {
    const float* x = (const float*)d_in[0];
    const float* f = (const float*)d_in[1];
    float* out = (float*)d_out;
    (void)in_sizes; (void)n_in; (void)d_ws; (void)ws_size; (void)out_size;

    dim3 blk(256);
    dim3 grid_main(D4 / 256, SEGS);   // (4, 128) = 512 blocks
    dim3 grid_scan(D4 / 256);         // 4 blocks

    comb_carry<<<grid_main, blk, 0, stream>>>(x, f);
    comb_scan<<<grid_scan, blk, 0, stream>>>(f);
    comb_emit<<<grid_main, blk, 0, stream>>>(x, f, out);
}